// Round 1
// baseline (1833.676 us; speedup 1.0000x reference)
//
#include <hip/hip_runtime.h>

typedef __attribute__((ext_vector_type(8))) short short8;
typedef __attribute__((ext_vector_type(8))) unsigned short ushortx8;
typedef __attribute__((ext_vector_type(4))) unsigned short ushortx4;
typedef __attribute__((ext_vector_type(4))) float floatx4;

#define SCALE_F 0.08838834764831845f  // 128^-0.5

__device__ __forceinline__ float b2f(unsigned short u) {
  union { unsigned int u; float f; } c; c.u = ((unsigned int)u) << 16; return c.f;
}
__device__ __forceinline__ unsigned short f2b(float f) {
  union { float f; unsigned int u; } c; c.f = f;
  unsigned int u = c.u;
  u += 0x7fffu + ((u >> 16) & 1u);  // RNE; inputs never NaN
  return (unsigned short)(u >> 16);
}

// ---------------------------------------------------------------------------
// cast fp32 -> bf16 (vectorized x4)
// ---------------------------------------------------------------------------
__global__ __launch_bounds__(256) void cast_bf16_kernel(
    const float* __restrict__ x, unsigned short* __restrict__ y, int n) {
  int i = (blockIdx.x * 256 + threadIdx.x) * 4;
  if (i >= n) return;
  float4 v = *(const float4*)(x + i);
  ushortx4 o;
  o[0] = f2b(v.x); o[1] = f2b(v.y); o[2] = f2b(v.z); o[3] = f2b(v.w);
  *(ushortx4*)(y + i) = o;
}

// ---------------------------------------------------------------------------
// generic 32x32 tiled transpose, batched over (b,h) derived from p=pstart+z
// MODE 0: f32->bf16   1: f32->f32   2: bf16->bf16
// out[c][r] = in[r][c]; all dims here are multiples of 32
// ---------------------------------------------------------------------------
template<int MODE>
__global__ __launch_bounds__(256) void transpose_any(
    const void* __restrict__ inv, void* __restrict__ outv,
    int R, int C, int ldin, int ldout,
    long sIb, long sIh, long sOb, long sOh, int pstart) {
  int z = blockIdx.z, p = pstart + z, b = p >> 3, h = p & 7;
  size_t ioff = (size_t)(sIb * b + sIh * h);
  size_t ooff = (size_t)(sOb * b + sOh * h);
  __shared__ float tile[32][33];
  int t = threadIdx.x, tx = t & 31, ty = t >> 5;
  int c0 = blockIdx.x * 32, r0 = blockIdx.y * 32;
  for (int rr = ty; rr < 32; rr += 8) {
    size_t idx = ioff + (size_t)(r0 + rr) * ldin + (c0 + tx);
    tile[rr][tx] = (MODE == 2) ? b2f(((const unsigned short*)inv)[idx])
                               : ((const float*)inv)[idx];
  }
  __syncthreads();
  for (int rr = ty; rr < 32; rr += 8) {
    size_t idx = ooff + (size_t)(c0 + rr) * ldout + (r0 + tx);
    float v = tile[tx][rr];
    if (MODE == 1) ((float*)outv)[idx] = v;
    else           ((unsigned short*)outv)[idx] = f2b(v);
  }
}

// ---------------------------------------------------------------------------
// bf16 MFMA GEMM: C[M][N] = A[M][K] @ BT[N][K]^T   (i.e. B^T given row-major)
// 64x64 tile, BK=32, 256 threads = 4 waves, each wave a 32x32 quadrant
// mfma_f32_16x16x32_bf16 layouts (doc-verified):
//   A frag: A[m=lane&15][k=(lane>>4)*8+j], 8 contiguous bf16 -> ds_read_b128
//   B frag: B[k=(lane>>4)*8+j][n=lane&15] == BT[n=lane&15][k=..] (same pattern)
//   C/D  : col=lane&15, row=(lane>>4)*4+r
// batched via p=pstart+z, b=p>>3, h=p&7; off = sXz*z + sXb*b + sXh*h
// ---------------------------------------------------------------------------
template<int OUT_BF16, int ADD_BIAS>
__global__ __launch_bounds__(256) void gemm_bt_k(
    const unsigned short* __restrict__ A, const unsigned short* __restrict__ BT,
    void* __restrict__ Cv, const float* __restrict__ bias,
    int M, int N, int K, int lda, int ldb, int ldc,
    long sAz, long sAb, long sAh, long sBz, long sBb, long sBh,
    long sCz, long sCb, long sCh, int pstart) {
  int z = blockIdx.z, p = pstart + z, bb = p >> 3, hh = p & 7;
  A  += (size_t)(sAz * z + sAb * bb + sAh * hh);
  BT += (size_t)(sBz * z + sBb * bb + sBh * hh);
  size_t coff = (size_t)(sCz * z + sCb * bb + sCh * hh);

  __shared__ unsigned short Al[64][40];  // pad 32->40: 16B-aligned b128, banks spread
  __shared__ unsigned short Bl[64][40];
  int t = threadIdx.x;
  int m0 = blockIdx.y * 64, n0 = blockIdx.x * 64;
  int w = t >> 6, l = t & 63;
  int subm = (w >> 1) * 32, subn = (w & 1) * 32;
  int lrow = l & 15, lq = l >> 4;
  floatx4 acc[2][2] = {};
  int sr = t >> 2, sc = (t & 3) * 8;  // staging: 64 rows x 32 cols, 16B/lane

  for (int k0 = 0; k0 < K; k0 += 32) {
    *(ushortx8*)&Al[sr][sc] = *(const ushortx8*)(A + (size_t)(m0 + sr) * lda + k0 + sc);
    *(ushortx8*)&Bl[sr][sc] = *(const ushortx8*)(BT + (size_t)(n0 + sr) * ldb + k0 + sc);
    __syncthreads();
    short8 af0 = *(const short8*)&Al[subm + lrow][lq * 8];
    short8 af1 = *(const short8*)&Al[subm + 16 + lrow][lq * 8];
    short8 bf0 = *(const short8*)&Bl[subn + lrow][lq * 8];
    short8 bf1 = *(const short8*)&Bl[subn + 16 + lrow][lq * 8];
    acc[0][0] = __builtin_amdgcn_mfma_f32_16x16x32_bf16(af0, bf0, acc[0][0], 0, 0, 0);
    acc[0][1] = __builtin_amdgcn_mfma_f32_16x16x32_bf16(af0, bf1, acc[0][1], 0, 0, 0);
    acc[1][0] = __builtin_amdgcn_mfma_f32_16x16x32_bf16(af1, bf0, acc[1][0], 0, 0, 0);
    acc[1][1] = __builtin_amdgcn_mfma_f32_16x16x32_bf16(af1, bf1, acc[1][1], 0, 0, 0);
    __syncthreads();
  }
  for (int i = 0; i < 2; i++)
    for (int j = 0; j < 2; j++)
      for (int r = 0; r < 4; r++) {
        int row = m0 + subm + i * 16 + lq * 4 + r;
        int col = n0 + subn + j * 16 + lrow;
        float v = acc[i][j][r];
        if (ADD_BIAS) v += bias[col];
        size_t idx = coff + (size_t)row * ldc + col;
        if (OUT_BF16) ((unsigned short*)Cv)[idx] = f2b(v);
        else          ((float*)Cv)[idx] = v;
      }
}

// ---------------------------------------------------------------------------
// fp32 GEMM: C[M][N] = A[M][K] @ BT[N][K]^T ; 64x64 tile, BK=16, 4x4 micro-tile
// used for the precision-critical m-stream (qk projection + s_m logits)
// ---------------------------------------------------------------------------
__global__ __launch_bounds__(256) void gemm_f32bt(
    const float* __restrict__ A, const float* __restrict__ BT, float* __restrict__ C,
    int M, int N, int K, int lda, int ldb, int ldc,
    long sAz, long sAb, long sAh, long sBz, long sBb, long sBh,
    long sCz, long sCb, long sCh, int pstart) {
  int z = blockIdx.z, p = pstart + z, bb = p >> 3, hh = p & 7;
  A  += (size_t)(sAz * z + sAb * bb + sAh * hh);
  BT += (size_t)(sBz * z + sBb * bb + sBh * hh);
  C  += (size_t)(sCz * z + sCb * bb + sCh * hh);

  __shared__ float As[16][68];  // [k][m], pad 68 keeps float4 alignment
  __shared__ float Bs[16][68];  // [k][n]
  int t = threadIdx.x, tx = t & 15, ty = t >> 4;
  int m0 = blockIdx.y * 64, n0 = blockIdx.x * 64;
  float4 acc[4];
  acc[0] = make_float4(0.f, 0.f, 0.f, 0.f);
  acc[1] = acc[0]; acc[2] = acc[0]; acc[3] = acc[0];
  int sr = t >> 2, sc = (t & 3) * 4;

  for (int k0 = 0; k0 < K; k0 += 16) {
    float4 av = *(const float4*)(A + (size_t)(m0 + sr) * lda + k0 + sc);
    float4 bv = *(const float4*)(BT + (size_t)(n0 + sr) * ldb + k0 + sc);
    As[sc + 0][sr] = av.x; As[sc + 1][sr] = av.y; As[sc + 2][sr] = av.z; As[sc + 3][sr] = av.w;
    Bs[sc + 0][sr] = bv.x; Bs[sc + 1][sr] = bv.y; Bs[sc + 2][sr] = bv.z; Bs[sc + 3][sr] = bv.w;
    __syncthreads();
#pragma unroll
    for (int k = 0; k < 16; k++) {
      float4 a = *(const float4*)&As[k][ty * 4];
      float4 b = *(const float4*)&Bs[k][tx * 4];
      acc[0].x += a.x * b.x; acc[0].y += a.x * b.y; acc[0].z += a.x * b.z; acc[0].w += a.x * b.w;
      acc[1].x += a.y * b.x; acc[1].y += a.y * b.y; acc[1].z += a.y * b.z; acc[1].w += a.y * b.w;
      acc[2].x += a.z * b.x; acc[2].y += a.z * b.y; acc[2].z += a.z * b.z; acc[2].w += a.z * b.w;
      acc[3].x += a.w * b.x; acc[3].y += a.w * b.y; acc[3].z += a.w * b.z; acc[3].w += a.w * b.w;
    }
    __syncthreads();
  }
#pragma unroll
  for (int r = 0; r < 4; r++)
    *(float4*)(C + (size_t)(m0 + ty * 4 + r) * ldc + n0 + tx * 4) = acc[r];
}

// ---------------------------------------------------------------------------
// per-row fused: p_m = softmax(s_m row, fp32) ; dots = p_m * p_v * SCALE + g_l ;
// attn = softmax(dots) -> bf16, written in place over the p_v buffer
// one block (256 thr) per row; 4 elements per thread
// ---------------------------------------------------------------------------
__global__ __launch_bounds__(256) void softmax_combine(
    const float* __restrict__ smb, unsigned short* __restrict__ pvb,
    const float* __restrict__ g_l, int pstart) {
  int i = blockIdx.x, z = blockIdx.y;
  int p = pstart + z;
  const float* srow = smb + ((size_t)z * 1024 + i) * 1024;
  unsigned short* vrow = pvb + ((size_t)z * 1024 + i) * 1024;
  const float* grow = g_l + ((size_t)p * 1024 + i) * 1024;
  int t = threadIdx.x;
  __shared__ float red[4];

  float4 s = *(const float4*)(srow + t * 4);
  float mx = fmaxf(fmaxf(s.x, s.y), fmaxf(s.z, s.w));
#pragma unroll
  for (int o = 32; o; o >>= 1) mx = fmaxf(mx, __shfl_xor(mx, o));
  if ((t & 63) == 0) red[t >> 6] = mx;
  __syncthreads();
  mx = fmaxf(fmaxf(red[0], red[1]), fmaxf(red[2], red[3]));
  __syncthreads();
  float4 e;
  e.x = __expf(s.x - mx); e.y = __expf(s.y - mx);
  e.z = __expf(s.z - mx); e.w = __expf(s.w - mx);
  float sum = e.x + e.y + e.z + e.w;
#pragma unroll
  for (int o = 32; o; o >>= 1) sum += __shfl_xor(sum, o);
  if ((t & 63) == 0) red[t >> 6] = sum;
  __syncthreads();
  float inv = 1.0f / (red[0] + red[1] + red[2] + red[3]);
  __syncthreads();

  ushortx4 pv = *(const ushortx4*)(vrow + t * 4);
  float4 g = *(const float4*)(grow + t * 4);
  float4 d;
  d.x = e.x * inv * b2f(pv[0]) * SCALE_F + g.x;
  d.y = e.y * inv * b2f(pv[1]) * SCALE_F + g.y;
  d.z = e.z * inv * b2f(pv[2]) * SCALE_F + g.z;
  d.w = e.w * inv * b2f(pv[3]) * SCALE_F + g.w;

  float mx2 = fmaxf(fmaxf(d.x, d.y), fmaxf(d.z, d.w));
#pragma unroll
  for (int o = 32; o; o >>= 1) mx2 = fmaxf(mx2, __shfl_xor(mx2, o));
  if ((t & 63) == 0) red[t >> 6] = mx2;
  __syncthreads();
  mx2 = fmaxf(fmaxf(red[0], red[1]), fmaxf(red[2], red[3]));
  __syncthreads();
  float4 e2;
  e2.x = __expf(d.x - mx2); e2.y = __expf(d.y - mx2);
  e2.z = __expf(d.z - mx2); e2.w = __expf(d.w - mx2);
  float sum2 = e2.x + e2.y + e2.z + e2.w;
#pragma unroll
  for (int o = 32; o; o >>= 1) sum2 += __shfl_xor(sum2, o);
  if ((t & 63) == 0) red[t >> 6] = sum2;
  __syncthreads();
  float inv2 = 1.0f / (red[0] + red[1] + red[2] + red[3]);

  ushortx4 o4;
  o4[0] = f2b(e2.x * inv2); o4[1] = f2b(e2.y * inv2);
  o4[2] = f2b(e2.z * inv2); o4[3] = f2b(e2.w * inv2);
  *(ushortx4*)(vrow + t * 4) = o4;
}

// ---------------------------------------------------------------------------
// launch
// ---------------------------------------------------------------------------
extern "C" void kernel_launch(void* const* d_in, const int* in_sizes, int n_in,
                              void* d_out, int out_size, void* d_ws, size_t ws_size,
                              hipStream_t stream) {
  (void)in_sizes; (void)n_in; (void)out_size; (void)ws_size;
  const float* s_v   = (const float*)d_in[0];
  const float* s_m   = (const float*)d_in[1];
  const float* g_l   = (const float*)d_in[2];
  const float* W_qkv = (const float*)d_in[3];
  const float* W_qk  = (const float*)d_in[4];
  const float* W_out = (const float*)d_in[5];
  const float* b_out = (const float*)d_in[6];
  float* out = (float*)d_out;
  char* ws = (char*)d_ws;

  // workspace layout (285,212,672 bytes total)
  unsigned short* sv_bf = (unsigned short*)(ws);              // s_v bf16       16M
  unsigned short* wtqkv = (unsigned short*)(ws + 16777216);   // W_qkv^T bf16    6M
  unsigned short* wtout = (unsigned short*)(ws + 23068672);   // W_out^T bf16    2M
  float*          wtqk  = (float*)(ws + 25165824);            // W_qk^T  f32     8M
  unsigned short* qkvb  = (unsigned short*)(ws + 33554432);   // qkv bf16       48M
  float*          qkf   = (float*)(ws + 83886080);            // qk f32         64M
  unsigned short* vt    = (unsigned short*)(ws + 150994944);  // v^T bf16       16M
  unsigned short* ao    = (unsigned short*)(ws + 167772160);  // attn@v bf16    16M
  float*          smb   = (float*)(ws + 184549376);           // s_m chunk f32  64M
  unsigned short* pvb   = (unsigned short*)(ws + 251658240);  // p_v chunk bf16 32M

  // 1. cast s_v -> bf16
  cast_bf16_kernel<<<dim3(8192), 256, 0, stream>>>(s_v, sv_bf, 8388608);
  // 2-4. weight transposes
  transpose_any<0><<<dim3(96, 32, 1), 256, 0, stream>>>(
      W_qkv, wtqkv, 1024, 3072, 3072, 1024, 0, 0, 0, 0, 0);
  transpose_any<0><<<dim3(32, 32, 1), 256, 0, stream>>>(
      W_out, wtout, 1024, 1024, 1024, 1024, 0, 0, 0, 0, 0);
  transpose_any<1><<<dim3(64, 32, 1), 256, 0, stream>>>(
      W_qk, wtqk, 1024, 2048, 2048, 1024, 0, 0, 0, 0, 0);
  // 5. qkv = s_v @ W_qkv  (bf16 MFMA)
  gemm_bt_k<1, 0><<<dim3(48, 128, 1), 256, 0, stream>>>(
      sv_bf, wtqkv, qkvb, nullptr, 8192, 3072, 1024, 1024, 1024, 3072,
      0, 0, 0, 0, 0, 0, 0, 0, 0, 0);
  // 6. qk = s_m @ W_qk  (fp32 — precision-critical)
  gemm_f32bt<<<dim3(32, 128, 1), 256, 0, stream>>>(
      s_m, wtqk, qkf, 8192, 2048, 1024, 1024, 1024, 2048,
      0, 0, 0, 0, 0, 0, 0, 0, 0, 0);
  // 7. v^T per (b,h): vt[p][d][j]
  transpose_any<2><<<dim3(4, 32, 64), 256, 0, stream>>>(
      qkvb + 2048, vt, 1024, 128, 3072, 1024,
      (long)1024 * 3072, 128, (long)1048576, 131072, 0);

  // 8. chunks of 16 (b,h)-pairs
  for (int c = 0; c < 4; c++) {
    int pstart = c * 16;
    // s_m logits = q_m @ k_m^T (fp32)
    gemm_f32bt<<<dim3(16, 16, 16), 256, 0, stream>>>(
        qkf, qkf + 1024, smb, 1024, 1024, 128, 2048, 2048, 1024,
        0, (long)2048 * 1024, 128, 0, (long)2048 * 1024, 128,
        (long)1048576, 0, 0, pstart);
    // p_v = q_v @ k_v^T (bf16 MFMA)
    gemm_bt_k<1, 0><<<dim3(16, 16, 16), 256, 0, stream>>>(
        qkvb, qkvb + 1024, pvb, nullptr, 1024, 1024, 128, 3072, 3072, 1024,
        0, (long)1024 * 3072, 128, 0, (long)1024 * 3072, 128,
        (long)1048576, 0, 0, pstart);
    // fused double-softmax + combine -> attn (bf16, in place over pvb)
    softmax_combine<<<dim3(1024, 16), 256, 0, stream>>>(smb, pvb, g_l, pstart);
    // ao = attn @ v (bf16 MFMA), scattered into [b*1024+i][h*128+d]
    gemm_bt_k<1, 0><<<dim3(2, 16, 16), 256, 0, stream>>>(
        pvb, vt, ao, nullptr, 1024, 128, 1024, 1024, 1024, 1024,
        (long)1048576, 0, 0, 0, (long)1048576, 131072,
        0, (long)1048576, 128, pstart);
  }
  // 9. out = ao @ W_out + b_out (bf16 MFMA, fp32 out)
  gemm_bt_k<0, 1><<<dim3(16, 128, 1), 256, 0, stream>>>(
      ao, wtout, out, b_out, 8192, 1024, 1024, 1024, 1024, 1024,
      0, 0, 0, 0, 0, 0, 0, 0, 0, 0);
}

// Round 2
// 1139.711 us; speedup vs baseline: 1.6089x; 1.6089x over previous
//
#include <hip/hip_runtime.h>

typedef __attribute__((ext_vector_type(8))) short short8;
typedef __attribute__((ext_vector_type(8))) unsigned short ushortx8;
typedef __attribute__((ext_vector_type(4))) unsigned short ushortx4;
typedef __attribute__((ext_vector_type(4))) float floatx4;

#define SCALE_F 0.08838834764831845f  // 128^-0.5

__device__ __forceinline__ float b2f(unsigned short u) {
  union { unsigned int u; float f; } c; c.u = ((unsigned int)u) << 16; return c.f;
}
__device__ __forceinline__ unsigned short f2b(float f) {
  union { float f; unsigned int u; } c; c.f = f;
  unsigned int u = c.u;
  u += 0x7fffu + ((u >> 16) & 1u);  // RNE; inputs never NaN
  return (unsigned short)(u >> 16);
}

#define GLD_LDS16(g, l)                                              \
  __builtin_amdgcn_global_load_lds(                                  \
      (const __attribute__((address_space(1))) void*)(g),            \
      (__attribute__((address_space(3))) void*)(l), 16, 0, 0)

// ---------------------------------------------------------------------------
// cast fp32 -> bf16 (vectorized x4)
// ---------------------------------------------------------------------------
__global__ __launch_bounds__(256) void cast_bf16_kernel(
    const float* __restrict__ x, unsigned short* __restrict__ y, int n) {
  int i = (blockIdx.x * 256 + threadIdx.x) * 4;
  if (i >= n) return;
  float4 v = *(const float4*)(x + i);
  ushortx4 o;
  o[0] = f2b(v.x); o[1] = f2b(v.y); o[2] = f2b(v.z); o[3] = f2b(v.w);
  *(ushortx4*)(y + i) = o;
}

// ---------------------------------------------------------------------------
// split3: x[R][1024] f32 -> y[R][3072] bf16 = [hi | lo | hi]  (A' operand)
// ---------------------------------------------------------------------------
__global__ __launch_bounds__(256) void split3_kernel(
    const float* __restrict__ x, unsigned short* __restrict__ y) {
  int idx = blockIdx.x * 256 + threadIdx.x;
  int row = idx >> 8;            // 256 float4 per 1024-row
  int c4 = (idx & 255) * 4;
  float4 v = *(const float4*)(x + (size_t)row * 1024 + c4);
  ushortx4 hi, lo;
  hi[0] = f2b(v.x); lo[0] = f2b(v.x - b2f(hi[0]));
  hi[1] = f2b(v.y); lo[1] = f2b(v.y - b2f(hi[1]));
  hi[2] = f2b(v.z); lo[2] = f2b(v.z - b2f(hi[2]));
  hi[3] = f2b(v.w); lo[3] = f2b(v.w - b2f(hi[3]));
  unsigned short* yr = y + (size_t)row * 3072;
  *(ushortx4*)(yr + c4) = hi;
  *(ushortx4*)(yr + 1024 + c4) = lo;
  *(ushortx4*)(yr + 2048 + c4) = hi;
}

// ---------------------------------------------------------------------------
// transpose+split W_qk[1024][2048] f32 -> y[2048][3072] bf16 = [hi | hi | lo]
// ---------------------------------------------------------------------------
__global__ __launch_bounds__(256) void transpose_split_qk(
    const float* __restrict__ W, unsigned short* __restrict__ y) {
  __shared__ float tile[32][33];
  int t = threadIdx.x, tx = t & 31, ty = t >> 5;
  int n0 = blockIdx.x * 32, k0 = blockIdx.y * 32;
  for (int rr = ty; rr < 32; rr += 8)
    tile[rr][tx] = W[(size_t)(k0 + rr) * 2048 + n0 + tx];
  __syncthreads();
  for (int rr = ty; rr < 32; rr += 8) {
    float v = tile[tx][rr];
    unsigned short hi = f2b(v);
    unsigned short lo = f2b(v - b2f(hi));
    unsigned short* yr = y + (size_t)(n0 + rr) * 3072;
    yr[k0 + tx] = hi;
    yr[1024 + k0 + tx] = hi;
    yr[2048 + k0 + tx] = lo;
  }
}

// ---------------------------------------------------------------------------
// generic 32x32 tiled transpose, batched over (b,h) from p=pstart+z
// MODE 0: f32->bf16   2: bf16->bf16
// ---------------------------------------------------------------------------
template<int MODE>
__global__ __launch_bounds__(256) void transpose_any(
    const void* __restrict__ inv, void* __restrict__ outv,
    int R, int C, int ldin, int ldout,
    long sIb, long sIh, long sOb, long sOh, int pstart) {
  int z = blockIdx.z, p = pstart + z, b = p >> 3, h = p & 7;
  size_t ioff = (size_t)(sIb * b + sIh * h);
  size_t ooff = (size_t)(sOb * b + sOh * h);
  __shared__ float tile[32][33];
  int t = threadIdx.x, tx = t & 31, ty = t >> 5;
  int c0 = blockIdx.x * 32, r0 = blockIdx.y * 32;
  for (int rr = ty; rr < 32; rr += 8) {
    size_t idx = ioff + (size_t)(r0 + rr) * ldin + (c0 + tx);
    tile[rr][tx] = (MODE == 2) ? b2f(((const unsigned short*)inv)[idx])
                               : ((const float*)inv)[idx];
  }
  __syncthreads();
  for (int rr = ty; rr < 32; rr += 8) {
    size_t idx = ooff + (size_t)(c0 + rr) * ldout + (r0 + tx);
    ((unsigned short*)outv)[idx] = f2b(tile[tx][rr]);
  }
}

// ---------------------------------------------------------------------------
// m97-style bf16 MFMA GEMM: C[M][N] = A[M][K] @ BT[N][K]^T
// 128x128 tile, BK=32, 256 thr = 4 waves, wave = 64x64 quadrant = 4x4 MFMA
// global->LDS via global_load_lds width=16; LDS layout [128][32] UNPADDED so
// lds_off(lane) = wave_base + lane*16 (wave-uniform base requirement).
//   thread t stages rows t>>2 and 64+(t>>2), cols (t&3)*8 .. +8
// fragment layouts (doc-verified 16x16x32 bf16):
//   A: A[m=lane&15][k=(lane>>4)*8+j]; B via BT same pattern; C: col=lane&15,
//   row=(lane>>4)*4+r
// batched via p=pstart+z (b=p>>3,h=p&7); off = sXz*z + sXb*b + sXh*h
// ---------------------------------------------------------------------------
template<int OUT_BF16, int ADD_BIAS>
__global__ __launch_bounds__(256) void gemm128(
    const unsigned short* __restrict__ A, const unsigned short* __restrict__ BT,
    void* __restrict__ Cv, const float* __restrict__ bias,
    int K, int lda, int ldb, int ldc,
    long sAz, long sAb, long sAh, long sBz, long sBb, long sBh,
    long sCz, long sCb, long sCh, int pstart) {
  int z = blockIdx.z, p = pstart + z, bb = p >> 3, hh = p & 7;
  A  += (size_t)(sAz * z + sAb * bb + sAh * hh);
  BT += (size_t)(sBz * z + sBb * bb + sBh * hh);
  size_t coff = (size_t)(sCz * z + sCb * bb + sCh * hh);

  __shared__ unsigned short Al[128][32];
  __shared__ unsigned short Bl[128][32];
  int t = threadIdx.x;
  int m0 = blockIdx.y * 128, n0 = blockIdx.x * 128;
  int w = t >> 6, l = t & 63;
  int wm = (w >> 1) * 64, wn = (w & 1) * 64;
  int lrow = l & 15, lq = l >> 4;
  floatx4 acc[4][4] = {};

  int srow = t >> 2, scol = (t & 3) * 8;
  const unsigned short* ga = A + (size_t)(m0 + srow) * lda + scol;
  const unsigned short* gb = BT + (size_t)(n0 + srow) * ldb + scol;
  unsigned short* la = &Al[srow][scol];
  unsigned short* lb = &Bl[srow][scol];
  size_t lda64 = (size_t)64 * lda, ldb64 = (size_t)64 * ldb;

  for (int k0 = 0; k0 < K; k0 += 32) {
    GLD_LDS16(ga + k0, la);
    GLD_LDS16(ga + lda64 + k0, la + 64 * 32);
    GLD_LDS16(gb + k0, lb);
    GLD_LDS16(gb + ldb64 + k0, lb + 64 * 32);
    __syncthreads();
    short8 af[4], bf[4];
#pragma unroll
    for (int i = 0; i < 4; i++) af[i] = *(const short8*)&Al[wm + i * 16 + lrow][lq * 8];
#pragma unroll
    for (int j = 0; j < 4; j++) bf[j] = *(const short8*)&Bl[wn + j * 16 + lrow][lq * 8];
#pragma unroll
    for (int i = 0; i < 4; i++)
#pragma unroll
      for (int j = 0; j < 4; j++)
        acc[i][j] = __builtin_amdgcn_mfma_f32_16x16x32_bf16(af[i], bf[j], acc[i][j], 0, 0, 0);
    __syncthreads();
  }
#pragma unroll
  for (int i = 0; i < 4; i++)
#pragma unroll
    for (int j = 0; j < 4; j++)
#pragma unroll
      for (int r = 0; r < 4; r++) {
        int row = m0 + wm + i * 16 + lq * 4 + r;
        int col = n0 + wn + j * 16 + lrow;
        float v = acc[i][j][r];
        if (ADD_BIAS) v += bias[col];
        size_t idx = coff + (size_t)row * ldc + col;
        if (OUT_BF16) ((unsigned short*)Cv)[idx] = f2b(v);
        else          ((float*)Cv)[idx] = v;
      }
}

// ---------------------------------------------------------------------------
// logits prep (per 16-pair chunk): qkf fp32 -> qm[z][1024][384]=[hi|lo|hi],
//                                           km[z][1024][384]=[hi|hi|lo]
// ---------------------------------------------------------------------------
__global__ __launch_bounds__(256) void logits_prep(
    const float* __restrict__ qkf, unsigned short* __restrict__ qm,
    unsigned short* __restrict__ km, int pstart) {
  int idx = blockIdx.x * 256 + threadIdx.x;  // 0..32767 over (i, d4)
  int z = blockIdx.y;
  int i = idx >> 5;
  int d4 = (idx & 31) * 4;
  int p = pstart + z, b = p >> 3, h = p & 7;
  const float* row = qkf + ((size_t)(b * 1024 + i)) * 2048 + h * 128;
  ushortx4 hi, lo;

  float4 q = *(const float4*)(row + d4);
  hi[0] = f2b(q.x); lo[0] = f2b(q.x - b2f(hi[0]));
  hi[1] = f2b(q.y); lo[1] = f2b(q.y - b2f(hi[1]));
  hi[2] = f2b(q.z); lo[2] = f2b(q.z - b2f(hi[2]));
  hi[3] = f2b(q.w); lo[3] = f2b(q.w - b2f(hi[3]));
  unsigned short* qr = qm + ((size_t)z * 1024 + i) * 384;
  *(ushortx4*)(qr + d4) = hi;
  *(ushortx4*)(qr + 128 + d4) = lo;
  *(ushortx4*)(qr + 256 + d4) = hi;

  float4 k = *(const float4*)(row + 1024 + d4);
  hi[0] = f2b(k.x); lo[0] = f2b(k.x - b2f(hi[0]));
  hi[1] = f2b(k.y); lo[1] = f2b(k.y - b2f(hi[1]));
  hi[2] = f2b(k.z); lo[2] = f2b(k.z - b2f(hi[2]));
  hi[3] = f2b(k.w); lo[3] = f2b(k.w - b2f(hi[3]));
  unsigned short* kr = km + ((size_t)z * 1024 + i) * 384;
  *(ushortx4*)(kr + d4) = hi;
  *(ushortx4*)(kr + 128 + d4) = hi;
  *(ushortx4*)(kr + 256 + d4) = lo;
}

// ---------------------------------------------------------------------------
// per-row fused: p_m = softmax(s_m row) ; dots = p_m*p_v*SCALE + g_l ;
// attn = softmax(dots) -> bf16 in place over pvb.  block = 1 row, 256 thr
// ---------------------------------------------------------------------------
__global__ __launch_bounds__(256) void softmax_combine(
    const float* __restrict__ smb, unsigned short* __restrict__ pvb,
    const float* __restrict__ g_l, int pstart) {
  int i = blockIdx.x, z = blockIdx.y;
  int p = pstart + z;
  const float* srow = smb + ((size_t)z * 1024 + i) * 1024;
  unsigned short* vrow = pvb + ((size_t)z * 1024 + i) * 1024;
  const float* grow = g_l + ((size_t)p * 1024 + i) * 1024;
  int t = threadIdx.x;
  __shared__ float red[4];

  float4 s = *(const float4*)(srow + t * 4);
  float mx = fmaxf(fmaxf(s.x, s.y), fmaxf(s.z, s.w));
#pragma unroll
  for (int o = 32; o; o >>= 1) mx = fmaxf(mx, __shfl_xor(mx, o));
  if ((t & 63) == 0) red[t >> 6] = mx;
  __syncthreads();
  mx = fmaxf(fmaxf(red[0], red[1]), fmaxf(red[2], red[3]));
  __syncthreads();
  float4 e;
  e.x = __expf(s.x - mx); e.y = __expf(s.y - mx);
  e.z = __expf(s.z - mx); e.w = __expf(s.w - mx);
  float sum = e.x + e.y + e.z + e.w;
#pragma unroll
  for (int o = 32; o; o >>= 1) sum += __shfl_xor(sum, o);
  if ((t & 63) == 0) red[t >> 6] = sum;
  __syncthreads();
  float inv = 1.0f / (red[0] + red[1] + red[2] + red[3]);
  __syncthreads();

  ushortx4 pv = *(const ushortx4*)(vrow + t * 4);
  float4 g = *(const float4*)(grow + t * 4);
  float4 d;
  d.x = e.x * inv * b2f(pv[0]) * SCALE_F + g.x;
  d.y = e.y * inv * b2f(pv[1]) * SCALE_F + g.y;
  d.z = e.z * inv * b2f(pv[2]) * SCALE_F + g.z;
  d.w = e.w * inv * b2f(pv[3]) * SCALE_F + g.w;

  float mx2 = fmaxf(fmaxf(d.x, d.y), fmaxf(d.z, d.w));
#pragma unroll
  for (int o = 32; o; o >>= 1) mx2 = fmaxf(mx2, __shfl_xor(mx2, o));
  if ((t & 63) == 0) red[t >> 6] = mx2;
  __syncthreads();
  mx2 = fmaxf(fmaxf(red[0], red[1]), fmaxf(red[2], red[3]));
  __syncthreads();
  float4 e2;
  e2.x = __expf(d.x - mx2); e2.y = __expf(d.y - mx2);
  e2.z = __expf(d.z - mx2); e2.w = __expf(d.w - mx2);
  float sum2 = e2.x + e2.y + e2.z + e2.w;
#pragma unroll
  for (int o = 32; o; o >>= 1) sum2 += __shfl_xor(sum2, o);
  if ((t & 63) == 0) red[t >> 6] = sum2;
  __syncthreads();
  float inv2 = 1.0f / (red[0] + red[1] + red[2] + red[3]);

  ushortx4 o4;
  o4[0] = f2b(e2.x * inv2); o4[1] = f2b(e2.y * inv2);
  o4[2] = f2b(e2.z * inv2); o4[3] = f2b(e2.w * inv2);
  *(ushortx4*)(vrow + t * 4) = o4;
}

// ---------------------------------------------------------------------------
// launch
// ---------------------------------------------------------------------------
extern "C" void kernel_launch(void* const* d_in, const int* in_sizes, int n_in,
                              void* d_out, int out_size, void* d_ws, size_t ws_size,
                              hipStream_t stream) {
  (void)in_sizes; (void)n_in; (void)out_size; (void)ws_size;
  const float* s_v   = (const float*)d_in[0];
  const float* s_m   = (const float*)d_in[1];
  const float* g_l   = (const float*)d_in[2];
  const float* W_qkv = (const float*)d_in[3];
  const float* W_qk  = (const float*)d_in[4];
  const float* W_out = (const float*)d_in[5];
  const float* b_out = (const float*)d_in[6];
  float* out = (float*)d_out;
  char* ws = (char*)d_ws;

  // workspace (283,115,520 B total; phase-aliased regions marked A:/B:)
  unsigned short* sv_bf  = (unsigned short*)(ws);              // A: s_v bf16 16M
  unsigned short* qm384  = (unsigned short*)(ws);              // B: alias, 12.6M
  unsigned short* wtqkv  = (unsigned short*)(ws + 16777216);   // A: 6.3M
  unsigned short* km384  = (unsigned short*)(ws + 16777216);   // B: alias, 12.6M
  unsigned short* wtout  = (unsigned short*)(ws + 29360128);   // persistent 2M
  unsigned short* qkvb   = (unsigned short*)(ws + 31457280);   // persistent 48M
  float*          qkf    = (float*)(ws + 81788928);            // persistent 64M
  unsigned short* vt     = (unsigned short*)(ws + 148897792);  // persistent 16M
  unsigned short* ao     = (unsigned short*)(ws + 165675008);  // persistent 16M
  unsigned short* smhl   = (unsigned short*)(ws + 182452224);  // A: 48M
  float*          smb    = (float*)(ws + 182452224);           // B: alias, 64M
  unsigned short* wqk_hl = (unsigned short*)(ws + 249561088);  // A: 12.6M
  unsigned short* pvb    = (unsigned short*)(ws + 249561088);  // B: alias, 32M

  // 1. cast s_v -> bf16
  cast_bf16_kernel<<<dim3(8192), 256, 0, stream>>>(s_v, sv_bf, 8388608);
  // 2-3. weight transposes (bf16)
  transpose_any<0><<<dim3(96, 32, 1), 256, 0, stream>>>(
      W_qkv, wtqkv, 1024, 3072, 3072, 1024, 0, 0, 0, 0, 0);
  transpose_any<0><<<dim3(32, 32, 1), 256, 0, stream>>>(
      W_out, wtout, 1024, 1024, 1024, 1024, 0, 0, 0, 0, 0);
  // 4. split s_m -> [hi|lo|hi]  (8192 x 3072)
  split3_kernel<<<dim3(8192), 256, 0, stream>>>(s_m, smhl);
  // 5. transpose+split W_qk -> [2048][3072] = [hi|hi|lo]
  transpose_split_qk<<<dim3(64, 32, 1), 256, 0, stream>>>(W_qk, wqk_hl);
  // 6. qkv = s_v @ W_qkv  (bf16 MFMA 128-tile)
  gemm128<1, 0><<<dim3(24, 64, 1), 256, 0, stream>>>(
      sv_bf, wtqkv, qkvb, nullptr, 1024, 1024, 1024, 3072,
      0, 0, 0, 0, 0, 0, 0, 0, 0, 0);
  // 7. qk = s_m @ W_qk  in split-bf16 (K=3072), fp32 out — fp32-grade precision
  gemm128<0, 0><<<dim3(16, 64, 1), 256, 0, stream>>>(
      smhl, wqk_hl, qkf, nullptr, 3072, 3072, 3072, 2048,
      0, 0, 0, 0, 0, 0, 0, 0, 0, 0);
  // 8. v^T per (b,h): vt[p][d][j]
  transpose_any<2><<<dim3(4, 32, 64), 256, 0, stream>>>(
      qkvb + 2048, vt, 1024, 128, 3072, 1024,
      (long)1024 * 3072, 128, (long)1048576, 131072, 0);

  // 9. chunks of 16 (b,h)-pairs
  for (int c = 0; c < 4; c++) {
    int pstart = c * 16;
    // split q_m/k_m for this chunk
    logits_prep<<<dim3(128, 16), 256, 0, stream>>>(qkf, qm384, km384, pstart);
    // s_m logits = q_m @ k_m^T via split-bf16 (K=384), fp32 out
    gemm128<0, 0><<<dim3(8, 8, 16), 256, 0, stream>>>(
        qm384, km384, smb, nullptr, 384, 384, 384, 1024,
        (long)1024 * 384, 0, 0, (long)1024 * 384, 0, 0,
        (long)1048576, 0, 0, pstart);
    // p_v = q_v @ k_v^T (bf16, K=128)
    gemm128<1, 0><<<dim3(8, 8, 16), 256, 0, stream>>>(
        qkvb, qkvb + 1024, pvb, nullptr, 128, 3072, 3072, 1024,
        0, (long)1024 * 3072, 128, 0, (long)1024 * 3072, 128,
        (long)1048576, 0, 0, pstart);
    // fused double-softmax + combine -> attn (bf16, in place over pvb)
    softmax_combine<<<dim3(1024, 16), 256, 0, stream>>>(smb, pvb, g_l, pstart);
    // ao = attn @ v, scattered into [b*1024+i][h*128+d]
    gemm128<1, 0><<<dim3(1, 8, 16), 256, 0, stream>>>(
        pvb, vt, ao, nullptr, 1024, 1024, 1024, 1024,
        (long)1048576, 0, 0, 0, (long)1048576, 131072,
        0, (long)1048576, 128, pstart);
  }
  // 10. out = ao @ W_out + b_out (fp32 out)
  gemm128<0, 1><<<dim3(8, 64, 1), 256, 0, stream>>>(
      ao, wtout, out, b_out, 1024, 1024, 1024, 1024,
      0, 0, 0, 0, 0, 0, 0, 0, 0, 0);
}